// Round 1
// baseline (163.739 us; speedup 1.0000x reference)
//
#include <hip/hip_runtime.h>
#include <stdint.h>

constexpr int kN = 16384;
constexpr int kD = 256;
constexpr int TM = 256, TN = 256;   // block tile 256x256
constexpr int KB = kD / 2;          // fp4 row = 128 bytes

using floatx16 = __attribute__((ext_vector_type(16))) float;  // 32x32 MFMA C/D
using intx4    = __attribute__((ext_vector_type(4))) int;
using intx8    = __attribute__((ext_vector_type(8))) int;     // f8f6f4 operand

// fp32*16 -> fp4 e2m1 RNE. Codes 0..7 = {0,.5,1,1.5,2,3,4,6} ARE the bit
// patterns (monotone). Thresholds are the RNE midpoints. (R12-verified.)
__device__ __forceinline__ uint32_t q4(float x) {
    float y = fabsf(x * 16.f);
    uint32_t c = (y >= 0.25f) + (y >= 0.75f) + (y >= 1.25f) + (y >= 1.75f)
               + (y >= 2.5f)  + (y >= 3.5f)  + (y >= 5.0f);
    return c | (x < 0.f ? 8u : 0u);
}

// 8 elems -> one dword per matrix per thread (nibble i = elem 8*idx+i).
// Also zeroes the loss accumulator (replaces the memset dispatch).
__global__ __launch_bounds__(256)
void cvt_fp4_kernel(const float* __restrict__ a, const float* __restrict__ b,
                    unsigned int* __restrict__ oa, unsigned int* __restrict__ ob,
                    float* __restrict__ out) {
    int idx = blockIdx.x * 256 + threadIdx.x;
    if (idx == 0) *out = 0.f;
    float4 a0 = *(const float4*)(a + (size_t)idx * 8);
    float4 a1 = *(const float4*)(a + (size_t)idx * 8 + 4);
    float4 b0 = *(const float4*)(b + (size_t)idx * 8);
    float4 b1 = *(const float4*)(b + (size_t)idx * 8 + 4);
    uint32_t pa = q4(a0.x) | (q4(a0.y) << 4) | (q4(a0.z) << 8)  | (q4(a0.w) << 12)
                | (q4(a1.x) << 16) | (q4(a1.y) << 20) | (q4(a1.z) << 24) | (q4(a1.w) << 28);
    uint32_t pb = q4(b0.x) | (q4(b0.y) << 4) | (q4(b0.z) << 8)  | (q4(b0.w) << 12)
                | (q4(b1.x) << 16) | (q4(b1.y) << 20) | (q4(b1.z) << 24) | (q4(b1.w) << 28);
    oa[idx] = pa;
    ob[idx] = pb;
}

// Concat two quads into an 8-reg MFMA tuple (coalesces to adjacent regs).
#define CAT8(lo, hi) __builtin_shufflevector((lo), (hi), 0, 1, 2, 3, 4, 5, 6, 7)
// Rotate: odd quad into the low half; high half undef (fp4 reads only v[0:3]).
#define ROT8(v)      __builtin_shufflevector((v), (v), 4, 5, 6, 7, -1, -1, -1, -1)

// R14: software-pipelined half-tile epilogue. Per tile s the order is
//   loads(s) ; EPI half0(s-1) ; MFMA half0(s) ; EPI half1(s-1) ; MFMA half1(s)
// so every 64-elem Schraudolph epilogue slice issues on the VALU while the
// OTHER half's 16 MFMAs drain in the matrix pipe, and the tile's 8 B loads
// get a full epilogue slice (~400cy) of latency cover before first use.
// acc-reset movs are gone (first K-chunk MFMA takes C = z16), and operand
// tuples are stored natively as intx8 pairs {quad 2p, quad 2p+1}: even
// K-chunks are mov-free, odd K-chunks are a 4-mov rotate.
__global__ __launch_bounds__(512, 2)
void siglip_gemm_loss_kernel(const unsigned char* __restrict__ A,   // fp4 [N][KB]
                             const unsigned char* __restrict__ B,   // fp4 [N][KB]
                             const float* __restrict__ scale_p,
                             const float* __restrict__ bias_p,
                             float* __restrict__ out) {
    __shared__ float red[8];

    const int tid  = threadIdx.x;
    const int wave = tid >> 6;     // 0..7
    const int lane = tid & 63;

    const int g    = blockIdx.x;                  // 256 persistent blocks
    const int tRow = ((g & 7) << 3) + (g >> 5);   // fixed tile-row (A-stripe L2-hot)
    const int sCol = (g >> 3) & 3;                // tile s -> col sCol + 4s

    const int wr = wave >> 2, wc = wave & 3;   // 2x4 waves
    const int m0 = wr * 128, n0 = wc * 64;     // wave tile 128x64
    const int l31 = lane & 31;
    const int h   = lane >> 5;                 // K-half: byte offset 16h

    const float sc  = *scale_p * (1.0f / 256.0f);   // undo x16 x16 prescale
    const float bs  = *bias_p;
    const float sc3 = sc * (1.44269504f * 8388608.0f);
    const float bs3 = fmaf(bs, 1.44269504f * 8388608.0f, 1064986823.0f);

    // ---- A operand: loop-invariant, resident as intx8 pairs.
    // af8[i][p] = {quad 2p, quad 2p+1}; quad q = bytes q*32 + 16h of the row.
    intx8 af8[4][2];
    #pragma unroll
    for (int i = 0; i < 4; ++i) {
        const unsigned char* pa = A + ((size_t)tRow * TM + m0 + i * 32 + l31) * KB + 16 * h;
        #pragma unroll
        for (int p = 0; p < 2; ++p) {
            const intx4 lo = *(const intx4*)(pa + (2 * p) * 32);
            const intx4 hi = *(const intx4*)(pa + (2 * p + 1) * 32);
            af8[i][p] = CAT8(lo, hi);
        }
    }

    const floatx16 z16 = (floatx16)(0.f);   // persistent zero C operand

    floatx16 acc0[2][2];   // half 0: i in {0,1} x j in {0,1}
    floatx16 acc1[2][2];   // half 1: i in {2,3} x j in {0,1}
    float sm0 = 0.f, sm1 = 0.f, sm2 = 0.f, sm3 = 0.f;

    // B addressing: uniform SGPR base (bumped once per tile) + 32-bit voffset.
    const unsigned char* pb = B + (size_t)sCol * TN * KB;
    const int voff0 = (n0 + l31) * KB + 16 * h;         // j = 0 rows
    const int voff1 = voff0 + 32 * KB;                  // j = 1 rows
    const size_t tStride = (size_t)4 * TN * KB;         // tile col advances by 4

    intx8 bl[2][2];   // [j][p] = {quad 2p, quad 2p+1} of the current tile

    auto loadTile = [&]() {
        #pragma unroll
        for (int j = 0; j < 2; ++j) {
            const int vo = j ? voff1 : voff0;
            #pragma unroll
            for (int p = 0; p < 2; ++p) {
                const intx4 lo = *(const intx4*)(pb + vo + (2 * p) * 32);
                const intx4 hi = *(const intx4*)(pb + vo + (2 * p + 1) * 32);
                bl[j][p] = CAT8(lo, hi);
            }
        }
        pb += tStride;
    };

    auto mfmaHalf = [&](floatx16 (&acc)[2][2], const int ibase) {
        #pragma unroll
        for (int p = 0; p < 2; ++p) {
            // even K-chunk q = 2p: tuples are the stored pairs, mov-free
            #pragma unroll
            for (int ii = 0; ii < 2; ++ii) {
                const intx8 a = af8[ibase + ii][p];
                #pragma unroll
                for (int j = 0; j < 2; ++j)
                    acc[ii][j] = __builtin_amdgcn_mfma_scale_f32_32x32x64_f8f6f4(
                        a, bl[j][p], p == 0 ? z16 : acc[ii][j],
                        4 /*cbsz: A=fp4*/, 4 /*blgp: B=fp4*/,
                        0, 127, 0, 127 /*neutral e8m0 scales*/);
            }
            // odd K-chunk q = 2p+1: rotate odd quad into the low half
            const intx8 br0 = ROT8(bl[0][p]);
            const intx8 br1 = ROT8(bl[1][p]);
            #pragma unroll
            for (int ii = 0; ii < 2; ++ii) {
                const intx8 a = ROT8(af8[ibase + ii][p]);
                acc[ii][0] = __builtin_amdgcn_mfma_scale_f32_32x32x64_f8f6f4(
                    a, br0, acc[ii][0], 4, 4, 0, 127, 0, 127);
                acc[ii][1] = __builtin_amdgcn_mfma_scale_f32_32x32x64_f8f6f4(
                    a, br1, acc[ii][1], 4, 4, 0, 127, 0, 127);
            }
        }
    };

    // Schraudolph epilogue of one half (64 elems), 4-way partial sums.
    auto epiHalf = [&](const floatx16 (&acc)[2][2], const int ibase, const int tCol) {
        #pragma unroll
        for (int ii = 0; ii < 2; ++ii)
            #pragma unroll
            for (int j = 0; j < 2; ++j) {
                const floatx16 a = acc[ii][j];
                #pragma unroll
                for (int v = 0; v < 16; v += 4) {
                    sm0 += __int_as_float((int)fmaf(a[v + 0], sc3, bs3));
                    sm1 += __int_as_float((int)fmaf(a[v + 1], sc3, bs3));
                    sm2 += __int_as_float((int)fmaf(a[v + 2], sc3, bs3));
                    sm3 += __int_as_float((int)fmaf(a[v + 3], sc3, bs3));
                }
                // diagonal correction: term_diag = term_off - t
                const int gRow0 = tRow * TM + m0 + (ibase + ii) * 32;
                const int gCol0 = tCol * TN + n0 + j * 32;
                if (gRow0 == gCol0) {   // wave-uniform, rare
                    #pragma unroll
                    for (int v = 0; v < 16; ++v) {
                        const int rrow = (v & 3) + 8 * (v >> 2) + 4 * h;
                        if (rrow == l31)
                            sm0 -= fmaf(a[v], sc, bs);
                    }
                }
            }
    };

    // ---- pipelined main loop: EPI of tile s-1 rides under MFMAs of tile s
    loadTile();
    mfmaHalf(acc0, 0);
    mfmaHalf(acc1, 2);
    int tColPrev = sCol;                      // tile 0's column
    for (int s = 1; s < 16; ++s) {
        loadTile();                           // issue early: covered by epi half0
        epiHalf(acc0, 0, tColPrev);           // VALU || mfmaHalf1(s-1) drain
        mfmaHalf(acc0, 0);
        epiHalf(acc1, 2, tColPrev);           // VALU || mfmaHalf0(s) drain
        mfmaHalf(acc1, 2);
        tColPrev = sCol + 4 * s;
    }
    epiHalf(acc0, 0, tColPrev);               // drain tile 15
    epiHalf(acc1, 2, tColPrev);

    float sum = (sm0 + sm1) + (sm2 + sm3);

    // block reduce -> ONE atomicAdd per block (256 total, spread in time)
    #pragma unroll
    for (int off = 32; off > 0; off >>= 1)
        sum += __shfl_down(sum, off);
    if (lane == 0) red[wave] = sum;
    __syncthreads();
    if (tid == 0) {
        float s2 = 0.f;
        #pragma unroll
        for (int w = 0; w < 8; ++w) s2 += red[w];
        atomicAdd(out, s2 * (1.0f / (float)kN));
    }
}

extern "C" void kernel_launch(void* const* d_in, const int* in_sizes, int n_in,
                              void* d_out, int out_size, void* d_ws, size_t ws_size,
                              hipStream_t stream) {
    const float* img     = (const float*)d_in[0];
    const float* txt     = (const float*)d_in[1];
    const float* scale_p = (const float*)d_in[2];
    const float* bias_p  = (const float*)d_in[3];
    float* out = (float*)d_out;

    unsigned char* Af4 = (unsigned char*)d_ws;            // N*KB = 2 MiB
    unsigned char* Bf4 = Af4 + (size_t)kN * KB;           // 2 MiB

    cvt_fp4_kernel<<<dim3(kN * kD / 8 / 256), dim3(256), 0, stream>>>(
        img, txt, (unsigned int*)Af4, (unsigned int*)Bf4, out);
    siglip_gemm_loss_kernel<<<dim3(256), dim3(512), 0, stream>>>(
        Af4, Bf4, scale_p, bias_p, out);
}

// Round 2
// 121.226 us; speedup vs baseline: 1.3507x; 1.3507x over previous
//
#include <hip/hip_runtime.h>
#include <stdint.h>

constexpr int kN = 16384;
constexpr int kD = 256;
constexpr int TM = 256, TN = 256;   // block tile 256x256
constexpr int KB = kD / 2;          // fp4 row = 128 bytes

using floatx16 = __attribute__((ext_vector_type(16))) float;  // 32x32 MFMA C/D
using floatx2  = __attribute__((ext_vector_type(2))) float;   // v_pk_* pair
using intx2v   = __attribute__((ext_vector_type(2))) int;
using intx4    = __attribute__((ext_vector_type(4))) int;
using intx8    = __attribute__((ext_vector_type(8))) int;     // f8f6f4 operand

// fp32*16 -> fp4 e2m1 RNE. Codes 0..7 = {0,.5,1,1.5,2,3,4,6} ARE the bit
// patterns (monotone). Thresholds are the RNE midpoints. (R12-verified.)
__device__ __forceinline__ uint32_t q4(float x) {
    float y = fabsf(x * 16.f);
    uint32_t c = (y >= 0.25f) + (y >= 0.75f) + (y >= 1.25f) + (y >= 1.75f)
               + (y >= 2.5f)  + (y >= 3.5f)  + (y >= 5.0f);
    return c | (x < 0.f ? 8u : 0u);
}

// 8 elems -> one dword per matrix per thread (nibble i = elem 8*idx+i).
// Also zeroes the loss accumulator (replaces the memset dispatch).
__global__ __launch_bounds__(256)
void cvt_fp4_kernel(const float* __restrict__ a, const float* __restrict__ b,
                    unsigned int* __restrict__ oa, unsigned int* __restrict__ ob,
                    float* __restrict__ out) {
    int idx = blockIdx.x * 256 + threadIdx.x;
    if (idx == 0) *out = 0.f;
    float4 a0 = *(const float4*)(a + (size_t)idx * 8);
    float4 a1 = *(const float4*)(a + (size_t)idx * 8 + 4);
    float4 b0 = *(const float4*)(b + (size_t)idx * 8);
    float4 b1 = *(const float4*)(b + (size_t)idx * 8 + 4);
    uint32_t pa = q4(a0.x) | (q4(a0.y) << 4) | (q4(a0.z) << 8)  | (q4(a0.w) << 12)
                | (q4(a1.x) << 16) | (q4(a1.y) << 20) | (q4(a1.z) << 24) | (q4(a1.w) << 28);
    uint32_t pb = q4(b0.x) | (q4(b0.y) << 4) | (q4(b0.z) << 8)  | (q4(b0.w) << 12)
                | (q4(b1.x) << 16) | (q4(b1.y) << 20) | (q4(b1.z) << 24) | (q4(b1.w) << 28);
    oa[idx] = pa;
    ob[idx] = pb;
}

// Concat two quads into an 8-reg MFMA tuple (coalesces to adjacent regs).
#define CAT8(lo, hi) __builtin_shufflevector((lo), (hi), 0, 1, 2, 3, 4, 5, 6, 7)
// Rotate: odd quad into the low half; high half undef (fp4 reads only v[0:3];
// HW-validated in R14: absmax 0.0).
#define ROT8(v)      __builtin_shufflevector((v), (v), 4, 5, 6, 7, -1, -1, -1, -1)

// R15: temporally-halved accumulator pipeline. R14's lesson (WRITE_SIZE 28MB =
// scratch spill): two concurrently-live 64-reg acc halves + z16 + af8 hit the
// 256-reg/wave cap (pool 512/SIMD at 2 waves). Fix: ONE acc[2][2] (64 regs)
// reused for both row-halves of each tile. Schedule per tile s:
//   load(s) ; EPI h1(s-1) ; MFMA h0(s) ; EPI h0(s) ; MFMA h1(s)
// Every epilogue slice (VALU) issues while the previous MFMA half (~16x35cy)
// drains the matrix pipe; the 8 B-loads get a full epilogue of latency cover.
// Budget: af8 64 + acc 64 + bl 32 + z16 16 + misc ~25 = ~200 < 256. Epilogue
// is packed (v_pk_fma_f32 / v_pk_add_f32): 2 VALU/elem instead of 3.
__global__ __launch_bounds__(512, 2)
void siglip_gemm_loss_kernel(const unsigned char* __restrict__ A,   // fp4 [N][KB]
                             const unsigned char* __restrict__ B,   // fp4 [N][KB]
                             const float* __restrict__ scale_p,
                             const float* __restrict__ bias_p,
                             float* __restrict__ out) {
    __shared__ float red[8];

    const int tid  = threadIdx.x;
    const int wave = tid >> 6;     // 0..7
    const int lane = tid & 63;

    const int g    = blockIdx.x;                  // 256 persistent blocks
    const int tRow = ((g & 7) << 3) + (g >> 5);   // fixed tile-row (A-stripe L2-hot)
    const int sCol = (g >> 3) & 3;                // tile s -> col sCol + 4s

    const int wr = wave >> 2, wc = wave & 3;   // 2x4 waves
    const int m0 = wr * 128, n0 = wc * 64;     // wave tile 128x64
    const int l31 = lane & 31;
    const int h   = lane >> 5;                 // K-half: byte offset 16h

    const float sc  = *scale_p * (1.0f / 256.0f);   // undo x16 x16 prescale
    const float bs  = *bias_p;
    const float sc3 = sc * (1.44269504f * 8388608.0f);
    const float bs3 = fmaf(bs, 1.44269504f * 8388608.0f, 1064986823.0f);
    const floatx2 sc3v = (floatx2)(sc3);
    const floatx2 bs3v = (floatx2)(bs3);

    // ---- A operand: loop-invariant, resident as intx8 pairs.
    // af8[i][p] = {quad 2p, quad 2p+1}; quad q = bytes q*32 + 16h of the row.
    intx8 af8[4][2];
    #pragma unroll
    for (int i = 0; i < 4; ++i) {
        const unsigned char* pa = A + ((size_t)tRow * TM + m0 + i * 32 + l31) * KB + 16 * h;
        #pragma unroll
        for (int p = 0; p < 2; ++p) {
            const intx4 lo = *(const intx4*)(pa + (2 * p) * 32);
            const intx4 hi = *(const intx4*)(pa + (2 * p + 1) * 32);
            af8[i][p] = CAT8(lo, hi);
        }
    }

    const floatx16 z16 = (floatx16)(0.f);   // C operand of each half's first chunk

    floatx16 acc[2][2];     // ONE half-tile of accumulators, reused h0/h1
    floatx2 sm0 = (floatx2)(0.f), sm1 = (floatx2)(0.f);
    float smd = 0.f;        // diagonal correction accumulator

    // B addressing: uniform base (SGPR) bumped once per tile + 32-bit voffsets.
    const unsigned char* pb = B + (size_t)sCol * TN * KB;
    const int voff0 = (n0 + l31) * KB + 16 * h;         // j = 0 rows
    const int voff1 = voff0 + 32 * KB;                  // j = 1 rows
    const size_t tStride = (size_t)4 * TN * KB;         // tile col advances by 4

    intx8 bl[2][2];   // [j][p] = {quad 2p, quad 2p+1} of the current tile

    auto loadTile = [&]() {
        #pragma unroll
        for (int j = 0; j < 2; ++j) {
            const int vo = j ? voff1 : voff0;
            #pragma unroll
            for (int p = 0; p < 2; ++p) {
                const intx4 lo = *(const intx4*)(pb + vo + (2 * p) * 32);
                const intx4 hi = *(const intx4*)(pb + vo + (2 * p + 1) * 32);
                bl[j][p] = CAT8(lo, hi);
            }
        }
        pb += tStride;
    };

    // 16 MFMAs of one row-half (rows ibase..ibase+1 of the 4). First K-chunk
    // takes C = z16 (reset-free accumulate start).
    auto mfmaHalf = [&](const int ibase) {
        __builtin_amdgcn_s_setprio(1);
        #pragma unroll
        for (int p = 0; p < 2; ++p) {
            // even K-chunk q = 2p: tuples are the stored pairs, mov-free
            #pragma unroll
            for (int ii = 0; ii < 2; ++ii) {
                const intx8 a = af8[ibase + ii][p];
                #pragma unroll
                for (int j = 0; j < 2; ++j)
                    acc[ii][j] = __builtin_amdgcn_mfma_scale_f32_32x32x64_f8f6f4(
                        a, bl[j][p], p == 0 ? z16 : acc[ii][j],
                        4 /*cbsz: A=fp4*/, 4 /*blgp: B=fp4*/,
                        0, 127, 0, 127 /*neutral e8m0 scales*/);
            }
            // odd K-chunk q = 2p+1: rotate odd quad into the low half
            const intx8 br0 = ROT8(bl[0][p]);
            const intx8 br1 = ROT8(bl[1][p]);
            #pragma unroll
            for (int ii = 0; ii < 2; ++ii) {
                const intx8 a = ROT8(af8[ibase + ii][p]);
                acc[ii][0] = __builtin_amdgcn_mfma_scale_f32_32x32x64_f8f6f4(
                    a, br0, acc[ii][0], 4, 4, 0, 127, 0, 127);
                acc[ii][1] = __builtin_amdgcn_mfma_scale_f32_32x32x64_f8f6f4(
                    a, br1, acc[ii][1], 4, 4, 0, 127, 0, 127);
            }
        }
        __builtin_amdgcn_s_setprio(0);
    };

    // Schraudolph epilogue of one half (64 elems), packed 2-wide.
    auto epiHalf = [&](const int ibase, const int tCol) {
        #pragma unroll
        for (int ii = 0; ii < 2; ++ii)
            #pragma unroll
            for (int j = 0; j < 2; ++j) {
                const floatx16 a = acc[ii][j];
                #pragma unroll
                for (int v = 0; v < 16; v += 4) {
                    floatx2 t0 = {a[v + 0], a[v + 1]};
                    floatx2 t1 = {a[v + 2], a[v + 3]};
                    t0 = __builtin_elementwise_fma(t0, sc3v, bs3v);  // v_pk_fma_f32
                    t1 = __builtin_elementwise_fma(t1, sc3v, bs3v);
                    const intx2v e0 = {(int)t0.x, (int)t0.y};        // v_cvt_i32_f32
                    const intx2v e1 = {(int)t1.x, (int)t1.y};
                    sm0 += __builtin_bit_cast(floatx2, e0);          // v_pk_add_f32
                    sm1 += __builtin_bit_cast(floatx2, e1);
                }
                // diagonal correction: term_diag = term_off - t
                const int gRow0 = tRow * TM + m0 + (ibase + ii) * 32;
                const int gCol0 = tCol * TN + n0 + j * 32;
                if (gRow0 == gCol0) {   // wave-uniform, rare
                    #pragma unroll
                    for (int v = 0; v < 16; ++v) {
                        const int rrow = (v & 3) + 8 * (v >> 2) + 4 * h;
                        if (rrow == l31)
                            smd += fmaf(a[v], sc, bs);
                    }
                }
            }
    };

    // ---- pipelined main loop
    loadTile();                         // tile 0
    mfmaHalf(0);                        // h0(0)
    epiHalf(0, sCol);                   // E h0(0)  || h0(0) drain
    mfmaHalf(2);                        // h1(0)
    for (int s = 1; s < 16; ++s) {
        loadTile();                     // tile s   (covered by E h1(s-1))
        epiHalf(2, sCol + 4 * (s - 1)); // E h1(s-1) || h1(s-1) drain
        mfmaHalf(0);                    // h0(s)
        epiHalf(0, sCol + 4 * s);       // E h0(s)  || h0(s) drain
        mfmaHalf(2);                    // h1(s)
    }
    epiHalf(2, sCol + 60);              // drain tile 15 h1

    float sum = (sm0.x + sm1.x) + (sm0.y + sm1.y) - smd;

    // block reduce -> ONE atomicAdd per block (256 total, spread in time)
    #pragma unroll
    for (int off = 32; off > 0; off >>= 1)
        sum += __shfl_down(sum, off);
    if (lane == 0) red[wave] = sum;
    __syncthreads();
    if (tid == 0) {
        float s2 = 0.f;
        #pragma unroll
        for (int w = 0; w < 8; ++w) s2 += red[w];
        atomicAdd(out, s2 * (1.0f / (float)kN));
    }
}

extern "C" void kernel_launch(void* const* d_in, const int* in_sizes, int n_in,
                              void* d_out, int out_size, void* d_ws, size_t ws_size,
                              hipStream_t stream) {
    const float* img     = (const float*)d_in[0];
    const float* txt     = (const float*)d_in[1];
    const float* scale_p = (const float*)d_in[2];
    const float* bias_p  = (const float*)d_in[3];
    float* out = (float*)d_out;

    unsigned char* Af4 = (unsigned char*)d_ws;            // N*KB = 2 MiB
    unsigned char* Bf4 = Af4 + (size_t)kN * KB;           // 2 MiB

    cvt_fp4_kernel<<<dim3(kN * kD / 8 / 256), dim3(256), 0, stream>>>(
        img, txt, (unsigned int*)Af4, (unsigned int*)Bf4, out);
    siglip_gemm_loss_kernel<<<dim3(256), dim3(512), 0, stream>>>(
        Af4, Bf4, scale_p, bias_p, out);
}